// Round 11
// baseline (275.869 us; speedup 1.0000x reference)
//
#include <hip/hip_runtime.h>

typedef __fp16   f2  __attribute__((ext_vector_type(2)));
typedef _Float16 h4  __attribute__((ext_vector_type(4)));
typedef _Float16 v8h __attribute__((ext_vector_type(8)));
typedef float    v4f __attribute__((ext_vector_type(4)));
struct f2x2 { f2 lo, hi; };

#if __has_builtin(__builtin_amdgcn_exp2f)
#define FEXP2(x) __builtin_amdgcn_exp2f(x)   // raw v_exp_f32 (no ocml fixups)
#else
#define FEXP2(x) exp2f(x)
#endif

constexpr int Bn = 4, Nn = 2048, Dn = 1024, Hn = 16, DKn = 64, Mn = 8192;

// async global->LDS, 16B per lane; LDS dest = wave-uniform base + lane*16 (m104)
__device__ __forceinline__ void load_lds16(const _Float16* g, _Float16* l) {
    __builtin_amdgcn_global_load_lds(
        (const __attribute__((address_space(1))) void*)g,
        (__attribute__((address_space(3))) void*)l, 16, 0, 0);
}

// ---------------- elementwise fp32 -> f16 cast ----------------
__global__ __launch_bounds__(256) void cast_f16(const float* __restrict__ x,
                                                _Float16* __restrict__ y) {
    const int i = blockIdx.x * 256 + threadIdx.x;
    const float4 v = ((const float4*)x)[i];
    h4 o; o[0] = (_Float16)v.x; o[1] = (_Float16)v.y;
    o[2] = (_Float16)v.z; o[3] = (_Float16)v.w;
    ((h4*)y)[i] = o;
}

// ------- merged transpose+cast: 4 weights, W [k][n] fp32 -> Wt [n][k] f16 -------
__global__ __launch_bounds__(256) void castW4(const float* __restrict__ Wq,
                                              const float* __restrict__ Wk,
                                              const float* __restrict__ Wv,
                                              const float* __restrict__ Wo,
                                              _Float16* __restrict__ Wqkv,
                                              _Float16* __restrict__ Wto) {
    __shared__ float tile[32][33];
    const int which = blockIdx.x >> 10, bid = blockIdx.x & 1023;
    const float* W = which == 0 ? Wq : which == 1 ? Wk : which == 2 ? Wv : Wo;
    _Float16* Dst = which < 3 ? (Wqkv + ((size_t)which << 20)) : Wto;
    const int bx = bid & 31, by = bid >> 5;
    const int t = threadIdx.x;
    const int r = t >> 3, c4 = (t & 7) * 4;
    const float4 v = *(const float4*)&W[(size_t)(by * 32 + r) * Dn + bx * 32 + c4];
    tile[r][c4 + 0] = v.x; tile[r][c4 + 1] = v.y;
    tile[r][c4 + 2] = v.z; tile[r][c4 + 3] = v.w;
    __syncthreads();
    h4 o;
    o[0] = (_Float16)tile[c4 + 0][r];
    o[1] = (_Float16)tile[c4 + 1][r];
    o[2] = (_Float16)tile[c4 + 2][r];
    o[3] = (_Float16)tile[c4 + 3][r];
    *(h4*)&Dst[(size_t)(bx * 32 + r) * Dn + by * 32 + c4] = o;
}

// ======== BK=64 K-loop body (128x128 tile, gemmqkv) ========
#define GEMM_KLOOP64(Abase, Bbase)                                                  \
    v4f acc[4][4];                                                                  \
    _Pragma("unroll") for (int i = 0; i < 4; ++i)                                   \
        _Pragma("unroll") for (int j = 0; j < 4; ++j) acc[i][j] = v4f{0,0,0,0};     \
    for (int k0 = 0; k0 < Dn; k0 += 64) {                                           \
        __syncthreads();                                                            \
        _Pragma("unroll") for (int jj = 0; jj < 4; ++jj) {                          \
            const int ci = jj * 256 + w * 64 + lane;                                \
            const int rs = ci >> 3, cs = ci & 7;                                    \
            const int gc = (cs ^ (rs & 7)) * 8;                                     \
            load_lds16(Abase + (size_t)rs * Dn + k0 + gc, &As[(jj*256 + w*64) * 8]);\
            load_lds16(Bbase + (size_t)rs * Dn + k0 + gc, &Bs[(jj*256 + w*64) * 8]);\
        }                                                                           \
        __syncthreads();                                                            \
        _Pragma("unroll") for (int ks2 = 0; ks2 < 2; ++ks2) {                       \
            v8h a[4], b[4];                                                         \
            _Pragma("unroll") for (int i = 0; i < 4; ++i) {                         \
                const int ar = wm*64 + i*16 + l16;                                  \
                a[i] = *(const v8h*)&As[ar * 64 + (((ks2*4 + quad) ^ (ar & 7)) * 8)];\
            }                                                                       \
            _Pragma("unroll") for (int j = 0; j < 4; ++j) {                         \
                const int br = wn*64 + j*16 + l16;                                  \
                b[j] = *(const v8h*)&Bs[br * 64 + (((ks2*4 + quad) ^ (br & 7)) * 8)];\
            }                                                                       \
            _Pragma("unroll") for (int i = 0; i < 4; ++i)                           \
                _Pragma("unroll") for (int j = 0; j < 4; ++j)                       \
                    acc[i][j] = __builtin_amdgcn_mfma_f32_16x16x32_f16(a[i], b[j],  \
                                                                   acc[i][j],0,0,0);\
        }                                                                           \
    }

// ---------- fused QKV GEMM: [8192,1024] @ [3072,1024]^T ----------
__global__ __launch_bounds__(256) void gemmqkv(const _Float16* __restrict__ A,
                                               const _Float16* __restrict__ Wt,
                                               _Float16* __restrict__ Qo,
                                               _Float16* __restrict__ Ko,
                                               _Float16* __restrict__ Vo)
{
    __shared__ __align__(16) _Float16 As[128 * 64];
    __shared__ __align__(16) _Float16 Bs[128 * 64];
    const int t = threadIdx.x, lane = t & 63, w = t >> 6;
    const int quad = lane >> 4, l16 = lane & 15;
    const int wm = w >> 1, wn = w & 1;
    const int bx = blockIdx.x % 24, by = blockIdx.x / 24;
    const int m0 = by * 128, n0 = bx * 128;
    const _Float16* Abase = A + (size_t)m0 * Dn;
    const _Float16* Bbase = Wt + (size_t)n0 * Dn;

    GEMM_KLOOP64(Abase, Bbase)

    const int sec = n0 >> 10;                      // block-uniform: 0=Q 1=K 2=V
    if (sec < 2) {
        _Float16* C = sec ? Ko : Qo;
        // Q pre-scaled by 1/sqrt(DK) * log2(e) so flash uses exp2 directly
        const float scale = sec ? 1.0f : 0.125f * 1.44269504f;
#pragma unroll
        for (int i = 0; i < 4; ++i) {
            const int mbase = m0 + wm * 64 + i * 16 + quad * 4;
#pragma unroll
            for (int j = 0; j < 4; ++j) {
                const int nl = (n0 + wn * 64 + j * 16 + l16) & 1023;
                const int h = nl >> 6, dk = nl & 63;
#pragma unroll
                for (int r = 0; r < 4; ++r) {
                    const int m = mbase + r, b = m >> 11, nr = m & (Nn - 1);
                    C[((size_t)(b * Hn + h) * Nn + nr) * DKn + dk] = (_Float16)(acc[i][j][r] * scale);
                }
            }
        }
    } else {
#pragma unroll
        for (int i = 0; i < 4; ++i) {
            const int mbase = m0 + wm * 64 + i * 16 + quad * 4;
            const int b = mbase >> 11, nr = mbase & (Nn - 1);
#pragma unroll
            for (int j = 0; j < 4; ++j) {
                const int nl = (n0 + wn * 64 + j * 16 + l16) & 1023;
                const int h = nl >> 6, dk = nl & 63;
                h4 o; o[0] = (_Float16)acc[i][j][0]; o[1] = (_Float16)acc[i][j][1];
                o[2] = (_Float16)acc[i][j][2]; o[3] = (_Float16)acc[i][j][3];
                *(h4*)&Vo[((size_t)(b * Hn + h) * DKn + dk) * Nn + nr] = o;
            }
        }
    }
}

// ---------- output GEMM: [8192,1024] @ [1024,1024]^T -> fp32 row-major ----------
// 128m x 64n tiles -> 1024 blocks (4/CU vs old 2/CU), LDS 24KB, BK=64 swizzled.
__global__ __launch_bounds__(256) void gemmo(const _Float16* __restrict__ A,
                                             const _Float16* __restrict__ Wt,
                                             float* __restrict__ C)
{
    __shared__ __align__(16) _Float16 As[128 * 64];
    __shared__ __align__(16) _Float16 Bs[64 * 64];
    const int t = threadIdx.x, lane = t & 63, w = t >> 6;
    const int quad = lane >> 4, l16 = lane & 15;
    const int wm = w >> 1, wn = w & 1;                 // wave tile: 64m x 32n
    const int bx = blockIdx.x & 15, by = blockIdx.x >> 4;
    const int m0 = by * 128, n0 = bx * 64;
    const _Float16* Abase = A + (size_t)m0 * Dn;
    const _Float16* Bbase = Wt + (size_t)n0 * Dn;

    v4f acc[4][2];
#pragma unroll
    for (int i = 0; i < 4; ++i)
#pragma unroll
        for (int j = 0; j < 2; ++j) acc[i][j] = v4f{0.f, 0.f, 0.f, 0.f};

    for (int k0 = 0; k0 < Dn; k0 += 64) {
        __syncthreads();
#pragma unroll
        for (int jj = 0; jj < 4; ++jj) {               // A: 128 rows = 4 passes
            const int ci = jj * 256 + w * 64 + lane;
            const int rs = ci >> 3, cs = ci & 7;
            const int gc = (cs ^ (rs & 7)) * 8;
            load_lds16(Abase + (size_t)rs * Dn + k0 + gc, &As[(jj * 256 + w * 64) * 8]);
        }
#pragma unroll
        for (int jj = 0; jj < 2; ++jj) {               // B: 64 rows = 2 passes
            const int ci = jj * 256 + w * 64 + lane;
            const int rs = ci >> 3, cs = ci & 7;
            const int gc = (cs ^ (rs & 7)) * 8;
            load_lds16(Bbase + (size_t)rs * Dn + k0 + gc, &Bs[(jj * 256 + w * 64) * 8]);
        }
        __syncthreads();
#pragma unroll
        for (int ks2 = 0; ks2 < 2; ++ks2) {
            v8h a[4], b[2];
#pragma unroll
            for (int i = 0; i < 4; ++i) {
                const int ar = wm * 64 + i * 16 + l16;
                a[i] = *(const v8h*)&As[ar * 64 + (((ks2 * 4 + quad) ^ (ar & 7)) * 8)];
            }
#pragma unroll
            for (int j = 0; j < 2; ++j) {
                const int br = wn * 32 + j * 16 + l16;
                b[j] = *(const v8h*)&Bs[br * 64 + (((ks2 * 4 + quad) ^ (br & 7)) * 8)];
            }
#pragma unroll
            for (int i = 0; i < 4; ++i)
#pragma unroll
                for (int j = 0; j < 2; ++j)
                    acc[i][j] = __builtin_amdgcn_mfma_f32_16x16x32_f16(a[i], b[j], acc[i][j], 0, 0, 0);
        }
    }

#pragma unroll
    for (int i = 0; i < 4; ++i) {
        const int mbase = m0 + wm * 64 + i * 16 + quad * 4;
#pragma unroll
        for (int j = 0; j < 2; ++j) {
            const int n = n0 + wn * 32 + j * 16 + l16;
#pragma unroll
            for (int r = 0; r < 4; ++r)
                C[(size_t)(mbase + r) * Dn + n] = acc[i][j][r];
        }
    }
}

// ---------------- flash v5.1: native exp2, hoisted LDS offsets ----------------
__global__ __launch_bounds__(256) void flashv5(const _Float16* __restrict__ Q,
                                               const _Float16* __restrict__ K,
                                               const _Float16* __restrict__ Vt,
                                               _Float16* __restrict__ O)
{
    __shared__ __align__(16) _Float16 KS[64 * 64];     // [key][dk], chunk-swizzled
    __shared__ __align__(16) _Float16 VS[64 * 64];     // [dk][key], chunk-swizzled
    __shared__ __align__(16) _Float16 Ps[4][32 * 64];  // per-wave P, chunk-swizzled

    const int t = threadIdx.x;
    const int lane = t & 63, w = t >> 6;
    const int quad = lane >> 4, l16 = lane & 15;
    const int bh = blockIdx.x & 63;                    // fast-varying (L2 locality)
    const int qtile = 15 - (blockIdx.x >> 6);          // heaviest first
    const int b = bh >> 4, h = bh & 15;
    const int qb = qtile * 128 + w * 32;

    const _Float16* Qg = Q  + (size_t)bh * Nn * DKn;
    const _Float16* Kg = K  + (size_t)bh * Nn * DKn;
    const _Float16* Vg = Vt + (size_t)bh * DKn * Nn;

    auto stage = [&](int kt) {
        const int k0 = kt * 64;
#pragma unroll
        for (int jj = 0; jj < 2; ++jj) {
            const int ci = jj * 256 + w * 64 + lane;   // slot (r*8 + c)
            const int r = ci >> 3, c = ci & 7;
            const int gc = (c ^ (r & 7)) * 8;          // XOR chunk swizzle
            load_lds16(Kg + (size_t)(k0 + r) * DKn + gc, &KS[(jj * 256 + w * 64) * 8]);
            load_lds16(Vg + (size_t)r * Nn + k0 + gc,    &VS[(jj * 256 + w * 64) * 8]);
        }
    };

    v8h qf[2][2];
#pragma unroll
    for (int qq = 0; qq < 2; ++qq)
#pragma unroll
        for (int ks = 0; ks < 2; ++ks)
            qf[qq][ks] = *(const v8h*)&Qg[(size_t)(qb + qq * 16 + l16) * DKn + ks * 32 + quad * 8];

    // kt-invariant swizzled LDS offsets (int offsets: 1 VGPR each, 28 total)
    int koff[4][2], voff[4][2], pwoff[2][4], proff[2][2];
#pragma unroll
    for (int kk = 0; kk < 4; ++kk)
#pragma unroll
        for (int ks = 0; ks < 2; ++ks) {
            const int kr = kk * 16 + l16, kc = ks * 4 + quad;
            koff[kk][ks] = kr * 64 + ((kc ^ (kr & 7)) * 8);
            const int vr = kk * 16 + l16;              // nt plays kk's role for VS
            voff[kk][ks] = vr * 64 + ((kc ^ (vr & 7)) * 8);
        }
#pragma unroll
    for (int qq = 0; qq < 2; ++qq) {
        const int prow = qq * 16 + l16;
#pragma unroll
        for (int kk = 0; kk < 4; ++kk) {
            const int pch = kk * 2 + (quad >> 1);
            pwoff[qq][kk] = prow * 64 + ((pch ^ (prow & 7)) * 8 + (quad & 1) * 4);
        }
#pragma unroll
        for (int ks = 0; ks < 2; ++ks) {
            const int ach = ks * 4 + quad;
            proff[qq][ks] = prow * 64 + ((ach ^ (prow & 7)) * 8);
        }
    }

    v8h ones;
#pragma unroll
    for (int i = 0; i < 8; ++i) ones[i] = (_Float16)1.0f;

    v4f o[2][4];
#pragma unroll
    for (int mq = 0; mq < 2; ++mq)
#pragma unroll
        for (int nt = 0; nt < 4; ++nt) o[mq][nt] = v4f{0.f, 0.f, 0.f, 0.f};
    v4f ol[2] = {v4f{0.f, 0.f, 0.f, 0.f}, v4f{0.f, 0.f, 0.f, 0.f}};

    const int NKT  = 2 * qtile + 2;                    // block-uniform
    const int diag = 2 * qtile + (w >> 1);             // wave's masked tile

    for (int kt = 0; kt < NKT; ++kt) {
        stage(kt);
        __syncthreads();                               // drains vmcnt (staging done)
        if (kt <= diag) {
            const int k0 = kt * 64;
            auto ptile = [&](bool domask) {
#pragma unroll
                for (int kk = 0; kk < 4; ++kk) {
                    v4f s0 = v4f{0.f, 0.f, 0.f, 0.f}, s1 = v4f{0.f, 0.f, 0.f, 0.f};
#pragma unroll
                    for (int ks = 0; ks < 2; ++ks) {
                        const v8h ak = *(const v8h*)&KS[koff[kk][ks]];
                        s0 = __builtin_amdgcn_mfma_f32_16x16x32_f16(ak, qf[0][ks], s0, 0, 0, 0);
                        s1 = __builtin_amdgcn_mfma_f32_16x16x32_f16(ak, qf[1][ks], s1, 0, 0, 0);
                    }
                    const int key0 = k0 + kk * 16 + quad * 4;
#pragma unroll
                    for (int qq = 0; qq < 2; ++qq) {
                        const v4f sv = qq ? s1 : s0;
                        const int q = qb + qq * 16 + l16;
                        float p[4];
#pragma unroll
                        for (int r = 0; r < 4; ++r) {
                            float x = sv[r];
                            if (domask) x = (key0 + r > q) ? -1e9f : x;
                            p[r] = FEXP2(x);           // Q pre-scaled by log2e/8
                        }
                        f2x2 pkr;
                        pkr.lo = __builtin_amdgcn_cvt_pkrtz(p[0], p[1]);
                        pkr.hi = __builtin_amdgcn_cvt_pkrtz(p[2], p[3]);
                        const h4 pk = __builtin_bit_cast(h4, pkr);
                        *(h4*)&Ps[w][pwoff[qq][kk]] = pk;
                    }
                }
#pragma unroll
                for (int ks = 0; ks < 2; ++ks)
#pragma unroll
                    for (int mq = 0; mq < 2; ++mq) {
                        const v8h a = *(const v8h*)&Ps[w][proff[mq][ks]];
#pragma unroll
                        for (int nt = 0; nt < 4; ++nt) {
                            const v8h bvv = *(const v8h*)&VS[voff[nt][ks]];
                            o[mq][nt] = __builtin_amdgcn_mfma_f32_16x16x32_f16(a, bvv, o[mq][nt], 0, 0, 0);
                        }
                        ol[mq] = __builtin_amdgcn_mfma_f32_16x16x32_f16(a, ones, ol[mq], 0, 0, 0);
                    }
            };
            if (kt == diag) ptile(true); else ptile(false);
        }
        __syncthreads();                               // all reads done before next stage
    }

    _Float16* Op = O + (size_t)b * Nn * Dn + h * DKn;
#pragma unroll
    for (int mq = 0; mq < 2; ++mq)
#pragma unroll
        for (int r = 0; r < 4; ++r) {
            const float li = 1.0f / ol[mq][r];
            const int qrow = qb + mq * 16 + quad * 4 + r;
#pragma unroll
            for (int nt = 0; nt < 4; ++nt)
                Op[(size_t)qrow * Dn + nt * 16 + l16] = (_Float16)(o[mq][nt][r] * li);
        }
}

extern "C" void kernel_launch(void* const* d_in, const int* in_sizes, int n_in,
                              void* d_out, int out_size, void* d_ws, size_t ws_size,
                              hipStream_t stream)
{
    const float* X  = (const float*)d_in[0];
    // d_in[1] = additive causal mask; regenerated inline in flashv5.
    const float* Wq = (const float*)d_in[2];
    const float* Wk = (const float*)d_in[3];
    const float* Wv = (const float*)d_in[4];
    const float* Wo = (const float*)d_in[5];

    char* ws = (char*)d_ws;
    _Float16* Xh   = (_Float16*)ws;                      // 16 MB
    _Float16* Wqkv = (_Float16*)(ws + (16u << 20));      // 6 MB  [3072][1024]
    _Float16* Wto  = Wqkv + (3u << 20);                  // 2 MB
    _Float16* Qh   = Wto + (1u << 20);                   // 16 MB each
    _Float16* Kh   = Qh + (size_t)Mn * Dn;
    _Float16* Vth  = Kh + (size_t)Mn * Dn;
    _Float16* Ah   = Vth + (size_t)Mn * Dn;              // total 88 MB

    cast_f16<<<(Mn * Dn / 4) / 256, 256, 0, stream>>>(X, Xh);
    castW4<<<4096, 256, 0, stream>>>(Wq, Wk, Wv, Wo, Wqkv, Wto);
    gemmqkv<<<64 * 24, 256, 0, stream>>>(Xh, Wqkv, Qh, Kh, Vth);
    flashv5<<<1024, 256, 0, stream>>>(Qh, Kh, Vth, Ah);
    gemmo<<<1024, 256, 0, stream>>>(Ah, Wto, (float*)d_out);
}

// Round 12
// 254.771 us; speedup vs baseline: 1.0828x; 1.0828x over previous
//
#include <hip/hip_runtime.h>

typedef __fp16   f2  __attribute__((ext_vector_type(2)));
typedef _Float16 h4  __attribute__((ext_vector_type(4)));
typedef _Float16 v8h __attribute__((ext_vector_type(8)));
typedef float    v4f __attribute__((ext_vector_type(4)));
struct f2x2 { f2 lo, hi; };

#if __has_builtin(__builtin_amdgcn_exp2f)
#define FEXP2(x) __builtin_amdgcn_exp2f(x)   // raw v_exp_f32 (no ocml fixups)
#else
#define FEXP2(x) exp2f(x)
#endif

constexpr int Bn = 4, Nn = 2048, Dn = 1024, Hn = 16, DKn = 64, Mn = 8192;

// async global->LDS, 16B per lane; LDS dest = wave-uniform base + lane*16 (m104)
__device__ __forceinline__ void load_lds16(const _Float16* g, _Float16* l) {
    __builtin_amdgcn_global_load_lds(
        (const __attribute__((address_space(1))) void*)g,
        (__attribute__((address_space(3))) void*)l, 16, 0, 0);
}

// ---------------- elementwise fp32 -> f16 cast ----------------
__global__ __launch_bounds__(256) void cast_f16(const float* __restrict__ x,
                                                _Float16* __restrict__ y) {
    const int i = blockIdx.x * 256 + threadIdx.x;
    const float4 v = ((const float4*)x)[i];
    h4 o; o[0] = (_Float16)v.x; o[1] = (_Float16)v.y;
    o[2] = (_Float16)v.z; o[3] = (_Float16)v.w;
    ((h4*)y)[i] = o;
}

// ------- merged transpose+cast: 4 weights, W [k][n] fp32 -> Wt [n][k] f16 -------
__global__ __launch_bounds__(256) void castW4(const float* __restrict__ Wq,
                                              const float* __restrict__ Wk,
                                              const float* __restrict__ Wv,
                                              const float* __restrict__ Wo,
                                              _Float16* __restrict__ Wqkv,
                                              _Float16* __restrict__ Wto) {
    __shared__ float tile[32][33];
    const int which = blockIdx.x >> 10, bid = blockIdx.x & 1023;
    const float* W = which == 0 ? Wq : which == 1 ? Wk : which == 2 ? Wv : Wo;
    _Float16* Dst = which < 3 ? (Wqkv + ((size_t)which << 20)) : Wto;
    const int bx = bid & 31, by = bid >> 5;
    const int t = threadIdx.x;
    const int r = t >> 3, c4 = (t & 7) * 4;
    const float4 v = *(const float4*)&W[(size_t)(by * 32 + r) * Dn + bx * 32 + c4];
    tile[r][c4 + 0] = v.x; tile[r][c4 + 1] = v.y;
    tile[r][c4 + 2] = v.z; tile[r][c4 + 3] = v.w;
    __syncthreads();
    h4 o;
    o[0] = (_Float16)tile[c4 + 0][r];
    o[1] = (_Float16)tile[c4 + 1][r];
    o[2] = (_Float16)tile[c4 + 2][r];
    o[3] = (_Float16)tile[c4 + 3][r];
    *(h4*)&Dst[(size_t)(bx * 32 + r) * Dn + by * 32 + c4] = o;
}

// ======== BK=64 K-loop body (shared by both GEMMs) ========
// LDS tiles 128x64 f16 (16KB each). Slot c of row r holds global chunk c ^ (r&7)
// -> frag ds_read_b128 at the bank minimum (0 conflicts measured, R10).
#define GEMM_KLOOP64(Abase, Bbase)                                                  \
    v4f acc[4][4];                                                                  \
    _Pragma("unroll") for (int i = 0; i < 4; ++i)                                   \
        _Pragma("unroll") for (int j = 0; j < 4; ++j) acc[i][j] = v4f{0,0,0,0};     \
    for (int k0 = 0; k0 < Dn; k0 += 64) {                                           \
        __syncthreads();                                                            \
        _Pragma("unroll") for (int jj = 0; jj < 4; ++jj) {                          \
            const int ci = jj * 256 + w * 64 + lane;                                \
            const int rs = ci >> 3, cs = ci & 7;                                    \
            const int gc = (cs ^ (rs & 7)) * 8;                                     \
            load_lds16(Abase + (size_t)rs * Dn + k0 + gc, &As[(jj*256 + w*64) * 8]);\
            load_lds16(Bbase + (size_t)rs * Dn + k0 + gc, &Bs[(jj*256 + w*64) * 8]);\
        }                                                                           \
        __syncthreads();                                                            \
        _Pragma("unroll") for (int ks2 = 0; ks2 < 2; ++ks2) {                       \
            v8h a[4], b[4];                                                         \
            _Pragma("unroll") for (int i = 0; i < 4; ++i) {                         \
                const int ar = wm*64 + i*16 + l16;                                  \
                a[i] = *(const v8h*)&As[ar * 64 + (((ks2*4 + quad) ^ (ar & 7)) * 8)];\
            }                                                                       \
            _Pragma("unroll") for (int j = 0; j < 4; ++j) {                         \
                const int br = wn*64 + j*16 + l16;                                  \
                b[j] = *(const v8h*)&Bs[br * 64 + (((ks2*4 + quad) ^ (br & 7)) * 8)];\
            }                                                                       \
            _Pragma("unroll") for (int i = 0; i < 4; ++i)                           \
                _Pragma("unroll") for (int j = 0; j < 4; ++j)                       \
                    acc[i][j] = __builtin_amdgcn_mfma_f32_16x16x32_f16(a[i], b[j],  \
                                                                   acc[i][j],0,0,0);\
        }                                                                           \
    }

// ---------- fused QKV GEMM: [8192,1024] @ [3072,1024]^T ----------
__global__ __launch_bounds__(256) void gemmqkv(const _Float16* __restrict__ A,
                                               const _Float16* __restrict__ Wt,
                                               _Float16* __restrict__ Qo,
                                               _Float16* __restrict__ Ko,
                                               _Float16* __restrict__ Vo)
{
    __shared__ __align__(16) _Float16 As[128 * 64];
    __shared__ __align__(16) _Float16 Bs[128 * 64];
    const int t = threadIdx.x, lane = t & 63, w = t >> 6;
    const int quad = lane >> 4, l16 = lane & 15;
    const int wm = w >> 1, wn = w & 1;
    const int bx = blockIdx.x % 24, by = blockIdx.x / 24;
    const int m0 = by * 128, n0 = bx * 128;
    const _Float16* Abase = A + (size_t)m0 * Dn;
    const _Float16* Bbase = Wt + (size_t)n0 * Dn;

    GEMM_KLOOP64(Abase, Bbase)

    const int sec = n0 >> 10;                      // block-uniform: 0=Q 1=K 2=V
    if (sec < 2) {
        _Float16* C = sec ? Ko : Qo;
        // Q pre-scaled by 1/sqrt(DK) * log2(e) so flash uses exp2 directly
        const float scale = sec ? 1.0f : 0.125f * 1.44269504f;
#pragma unroll
        for (int i = 0; i < 4; ++i) {
            const int mbase = m0 + wm * 64 + i * 16 + quad * 4;
#pragma unroll
            for (int j = 0; j < 4; ++j) {
                const int nl = (n0 + wn * 64 + j * 16 + l16) & 1023;
                const int h = nl >> 6, dk = nl & 63;
#pragma unroll
                for (int r = 0; r < 4; ++r) {
                    const int m = mbase + r, b = m >> 11, nr = m & (Nn - 1);
                    C[((size_t)(b * Hn + h) * Nn + nr) * DKn + dk] = (_Float16)(acc[i][j][r] * scale);
                }
            }
        }
    } else {
#pragma unroll
        for (int i = 0; i < 4; ++i) {
            const int mbase = m0 + wm * 64 + i * 16 + quad * 4;
            const int b = mbase >> 11, nr = mbase & (Nn - 1);
#pragma unroll
            for (int j = 0; j < 4; ++j) {
                const int nl = (n0 + wn * 64 + j * 16 + l16) & 1023;
                const int h = nl >> 6, dk = nl & 63;
                h4 o; o[0] = (_Float16)acc[i][j][0]; o[1] = (_Float16)acc[i][j][1];
                o[2] = (_Float16)acc[i][j][2]; o[3] = (_Float16)acc[i][j][3];
                *(h4*)&Vo[((size_t)(b * Hn + h) * DKn + dk) * Nn + nr] = o;
            }
        }
    }
}

// ---------- output GEMM: [8192,1024] @ [1024,1024]^T -> fp32 row-major ----------
__global__ __launch_bounds__(256) void gemmo(const _Float16* __restrict__ A,
                                             const _Float16* __restrict__ Wt,
                                             float* __restrict__ C)
{
    __shared__ __align__(16) _Float16 As[128 * 64];
    __shared__ __align__(16) _Float16 Bs[128 * 64];
    const int t = threadIdx.x, lane = t & 63, w = t >> 6;
    const int quad = lane >> 4, l16 = lane & 15;
    const int wm = w >> 1, wn = w & 1;
    const int bx = blockIdx.x & 7, by = blockIdx.x >> 3;
    const int m0 = by * 128, n0 = bx * 128;
    const _Float16* Abase = A + (size_t)m0 * Dn;
    const _Float16* Bbase = Wt + (size_t)n0 * Dn;

    GEMM_KLOOP64(Abase, Bbase)

#pragma unroll
    for (int i = 0; i < 4; ++i) {
        const int mbase = m0 + wm * 64 + i * 16 + quad * 4;
#pragma unroll
        for (int j = 0; j < 4; ++j) {
            const int n = n0 + wn * 64 + j * 16 + l16;
#pragma unroll
            for (int r = 0; r < 4; ++r)
                C[(size_t)(mbase + r) * Dn + n] = acc[i][j][r];
        }
    }
}

// ---------------- flash v5 (R10 best) + native exp2 only ----------------
__global__ __launch_bounds__(256) void flashv5(const _Float16* __restrict__ Q,
                                               const _Float16* __restrict__ K,
                                               const _Float16* __restrict__ Vt,
                                               _Float16* __restrict__ O)
{
    __shared__ __align__(16) _Float16 KS[64 * 64];     // [key][dk], chunk-swizzled
    __shared__ __align__(16) _Float16 VS[64 * 64];     // [dk][key], chunk-swizzled
    __shared__ __align__(16) _Float16 Ps[4][32 * 64];  // per-wave P, chunk-swizzled

    const int t = threadIdx.x;
    const int lane = t & 63, w = t >> 6;
    const int quad = lane >> 4, l16 = lane & 15;
    const int bh = blockIdx.x & 63;                    // fast-varying (L2 locality)
    const int qtile = 15 - (blockIdx.x >> 6);          // heaviest first
    const int b = bh >> 4, h = bh & 15;
    const int qb = qtile * 128 + w * 32;

    const _Float16* Qg = Q  + (size_t)bh * Nn * DKn;
    const _Float16* Kg = K  + (size_t)bh * Nn * DKn;
    const _Float16* Vg = Vt + (size_t)bh * DKn * Nn;

    auto stage = [&](int kt) {
        const int k0 = kt * 64;
#pragma unroll
        for (int jj = 0; jj < 2; ++jj) {
            const int ci = jj * 256 + w * 64 + lane;   // slot (r*8 + c)
            const int r = ci >> 3, c = ci & 7;
            const int gc = (c ^ (r & 7)) * 8;          // XOR chunk swizzle
            load_lds16(Kg + (size_t)(k0 + r) * DKn + gc, &KS[(jj * 256 + w * 64) * 8]);
            load_lds16(Vg + (size_t)r * Nn + k0 + gc,    &VS[(jj * 256 + w * 64) * 8]);
        }
    };
#define SWZ(arr, r, c) (*(const v8h*)&(arr)[(r) * 64 + (((c) ^ ((r) & 7)) * 8)])

    v8h qf[2][2];
#pragma unroll
    for (int qq = 0; qq < 2; ++qq)
#pragma unroll
        for (int ks = 0; ks < 2; ++ks)
            qf[qq][ks] = *(const v8h*)&Qg[(size_t)(qb + qq * 16 + l16) * DKn + ks * 32 + quad * 8];

    v8h ones;
#pragma unroll
    for (int i = 0; i < 8; ++i) ones[i] = (_Float16)1.0f;

    v4f o[2][4];
#pragma unroll
    for (int mq = 0; mq < 2; ++mq)
#pragma unroll
        for (int nt = 0; nt < 4; ++nt) o[mq][nt] = v4f{0.f, 0.f, 0.f, 0.f};
    v4f ol[2] = {v4f{0.f, 0.f, 0.f, 0.f}, v4f{0.f, 0.f, 0.f, 0.f}};

    const int NKT  = 2 * qtile + 2;                    // block-uniform
    const int diag = 2 * qtile + (w >> 1);             // wave's masked tile

    for (int kt = 0; kt < NKT; ++kt) {
        stage(kt);
        __syncthreads();                               // drains vmcnt (staging done)
        if (kt <= diag) {
            const int k0 = kt * 64;
            auto ptile = [&](bool domask) {
#pragma unroll
                for (int kk = 0; kk < 4; ++kk) {
                    v4f s0 = v4f{0.f, 0.f, 0.f, 0.f}, s1 = v4f{0.f, 0.f, 0.f, 0.f};
#pragma unroll
                    for (int ks = 0; ks < 2; ++ks) {
                        const v8h ak = SWZ(KS, kk * 16 + l16, ks * 4 + quad);
                        s0 = __builtin_amdgcn_mfma_f32_16x16x32_f16(ak, qf[0][ks], s0, 0, 0, 0);
                        s1 = __builtin_amdgcn_mfma_f32_16x16x32_f16(ak, qf[1][ks], s1, 0, 0, 0);
                    }
                    const int key0 = k0 + kk * 16 + quad * 4;
#pragma unroll
                    for (int qq = 0; qq < 2; ++qq) {
                        const v4f sv = qq ? s1 : s0;
                        const int q = qb + qq * 16 + l16;
                        float p[4];
#pragma unroll
                        for (int r = 0; r < 4; ++r) {
                            float x = sv[r];
                            if (domask) x = (key0 + r > q) ? -1e9f : x;
                            p[r] = FEXP2(x);           // Q pre-scaled by log2e/8
                        }
                        f2x2 pkr;
                        pkr.lo = __builtin_amdgcn_cvt_pkrtz(p[0], p[1]);
                        pkr.hi = __builtin_amdgcn_cvt_pkrtz(p[2], p[3]);
                        const h4 pk = __builtin_bit_cast(h4, pkr);
                        const int prow = qq * 16 + l16;
                        const int pch  = kk * 2 + (quad >> 1);
                        *(h4*)&Ps[w][prow * 64 + ((pch ^ (prow & 7)) * 8 + (quad & 1) * 4)] = pk;
                    }
                }
#pragma unroll
                for (int ks = 0; ks < 2; ++ks)
#pragma unroll
                    for (int mq = 0; mq < 2; ++mq) {
                        const int arow = mq * 16 + l16;
                        const int ach  = ks * 4 + quad;
                        const v8h a = *(const v8h*)&Ps[w][arow * 64 + ((ach ^ (arow & 7)) * 8)];
#pragma unroll
                        for (int nt = 0; nt < 4; ++nt) {
                            const v8h bvv = SWZ(VS, nt * 16 + l16, ks * 4 + quad);
                            o[mq][nt] = __builtin_amdgcn_mfma_f32_16x16x32_f16(a, bvv, o[mq][nt], 0, 0, 0);
                        }
                        ol[mq] = __builtin_amdgcn_mfma_f32_16x16x32_f16(a, ones, ol[mq], 0, 0, 0);
                    }
            };
            if (kt == diag) ptile(true); else ptile(false);
        }
        __syncthreads();                               // all reads done before next stage
    }
#undef SWZ

    _Float16* Op = O + (size_t)b * Nn * Dn + h * DKn;
#pragma unroll
    for (int mq = 0; mq < 2; ++mq)
#pragma unroll
        for (int r = 0; r < 4; ++r) {
            const float li = 1.0f / ol[mq][r];
            const int qrow = qb + mq * 16 + quad * 4 + r;
#pragma unroll
            for (int nt = 0; nt < 4; ++nt)
                Op[(size_t)qrow * Dn + nt * 16 + l16] = (_Float16)(o[mq][nt][r] * li);
        }
}

extern "C" void kernel_launch(void* const* d_in, const int* in_sizes, int n_in,
                              void* d_out, int out_size, void* d_ws, size_t ws_size,
                              hipStream_t stream)
{
    const float* X  = (const float*)d_in[0];
    // d_in[1] = additive causal mask; regenerated inline in flashv5.
    const float* Wq = (const float*)d_in[2];
    const float* Wk = (const float*)d_in[3];
    const float* Wv = (const float*)d_in[4];
    const float* Wo = (const float*)d_in[5];

    char* ws = (char*)d_ws;
    _Float16* Xh   = (_Float16*)ws;                      // 16 MB
    _Float16* Wqkv = (_Float16*)(ws + (16u << 20));      // 6 MB  [3072][1024]
    _Float16* Wto  = Wqkv + (3u << 20);                  // 2 MB
    _Float16* Qh   = Wto + (1u << 20);                   // 16 MB each
    _Float16* Kh   = Qh + (size_t)Mn * Dn;
    _Float16* Vth  = Kh + (size_t)Mn * Dn;
    _Float16* Ah   = Vth + (size_t)Mn * Dn;              // total 88 MB

    cast_f16<<<(Mn * Dn / 4) / 256, 256, 0, stream>>>(X, Xh);
    castW4<<<4096, 256, 0, stream>>>(Wq, Wk, Wv, Wo, Wqkv, Wto);
    gemmqkv<<<64 * 24, 256, 0, stream>>>(Xh, Wqkv, Qh, Kh, Vth);
    flashv5<<<1024, 256, 0, stream>>>(Qh, Kh, Vth, Ah);
    gemmo<<<512, 256, 0, stream>>>(Ah, Wto, (float*)d_out);
}